// Round 1
// baseline (112.576 us; speedup 1.0000x reference)
//
#include <hip/hip_runtime.h>
#include <math.h>

#define NNODES 512
#define CIN 8
#define COUT 8
#define RR 8
#define BTB 2                          // bt items per block (2 waves per bt)
#define GUARD 64                       // zeroed guard node-slots each side
#define SLOTS (GUARD + NNODES + GUARD) // 640 node slots per bt
#define SLAB_HW (SLOTS * 8)            // 5120 halfwords per bt (16 B per node slot)
#define LDS_HW (BTB * SLAB_HW)         // 10240 hw = 20480 B -> 4+ blocks/CU

typedef __attribute__((ext_vector_type(8))) short short8;
typedef __attribute__((ext_vector_type(4))) float floatx4;

__device__ __forceinline__ unsigned int pack_bf16(float a, float b) {
    unsigned int ua = __float_as_uint(a);
    unsigned int ub = __float_as_uint(b);
    ua = (ua + 0x7fffu + ((ua >> 16) & 1u)) >> 16;
    ub = (ub + 0x7fffu + ((ub >> 16) & 1u)) & 0xffff0000u;
    return ua | ub;
}

// Single fused kernel: no prep pass, no offset table.
//   - weights folded per-thread from conv_w/mix_w/alpha (L2-resident, overlaps staging)
//   - gather offsets derived on the fly: 2 stencil offsets via arithmetic,
//     2 random offsets via coalesced rand_idx loads (8 B/lane/iter, L1-hot)
// MFMA i covers taps {4i..4i+3}; quad q holds tap 4i+q.
// taps: 0 center, 1 d-, 2 d+, 3 h-, 4 h+, 5 w-, 6 w+, 7..14 g0..g7, 15 zero.
// per-quad roles: q0:{center,h+,g1,g5} q1:{d-,w-,g2,g6} q2:{d+,w+,g3,g7} q3:{h-,g0,g4,zero}
__global__ __launch_bounds__(256) void hybrid3d_v4(
    const float* __restrict__ x,
    const float* __restrict__ conv_w,
    const float* __restrict__ conv_b,
    const float* __restrict__ mix_w,
    const float* __restrict__ mix_b,
    const float* __restrict__ alpha_p,
    const int*   __restrict__ rand_idx,
    float* __restrict__ out)
{
    __shared__ unsigned short lds16[LDS_HW];
    const int tid  = threadIdx.x;
    const int wave = tid >> 6;
    const int lane = tid & 63;
    const int quad = lane >> 4;
    const int r16  = lane & 15;
    const int btl  = wave >> 1;     // bt within block (0..1)
    const int half = wave & 1;      // node-half handled by this wave

    // zero guard slots: 2 bt x 128 slots x 16 B -> exactly one uint4 per thread
    {
        const int b = tid >> 7;
        const int s = tid & 127;
        const int slot = (s < GUARD) ? s : (NNODES + s);   // 0..63 | 576..639
        *(uint4*)&lds16[b * SLAB_HW + slot * 8] = make_uint4(0u, 0u, 0u, 0u);
    }

    // stage x -> node-major bf16 slots (issue HBM loads first; weight loads overlap)
    const float* xg = x + ((size_t)blockIdx.x * BTB + btl) * (CIN * NNODES);
    unsigned short* slab = lds16 + btl * SLAB_HW;
#pragma unroll
    for (int j = 0; j < 4; ++j) {
        const int n = half * 256 + j * 64 + lane;
        float v[8];
#pragma unroll
        for (int c = 0; c < 8; ++c) v[c] = xg[c * NNODES + n];
        uint4 pk;
        pk.x = pack_bf16(v[0], v[1]);
        pk.y = pack_bf16(v[2], v[3]);
        pk.z = pack_bf16(v[4], v[5]);
        pk.w = pack_bf16(v[6], v[7]);
        *(uint4*)&slab[(GUARD + n) * 8] = pk;
    }

    // fold sigmoid(alpha) into B-fragments (identical arithmetic to old prep)
    const float aS = 1.0f / (1.0f + expf(-alpha_p[0]));
    const float aR = 1.0f - aS;
    short8 bfrag[4];
#pragma unroll
    for (int i = 0; i < 4; ++i) {
        const int tap = 4 * i + quad;
        union { unsigned int u[4]; short8 s; } bf;
#pragma unroll
        for (int jp = 0; jp < 4; ++jp) {
            float f0 = 0.0f, f1 = 0.0f;
            if (r16 < 8) {
                const int c0 = 2 * jp, c1 = c0 + 1;
                if (tap < 7) {
                    // (kd,kh,kw)->kd*9+kh*3+kw: center=13,d-=4,d+=22,h-=10,h+=16,w-=12,w+=14
                    const unsigned long long TAB =
                        13ull | (4ull << 8) | (22ull << 16) | (10ull << 24) |
                        (16ull << 32) | (12ull << 40) | (14ull << 48);
                    const int co = (int)((TAB >> (8 * tap)) & 0xffull);
                    f0 = aS * conv_w[(r16 * CIN + c0) * 27 + co];
                    f1 = aS * conv_w[(r16 * CIN + c1) * 27 + co];
                } else if (tap < 15) {
                    const int r = tap - 7;
                    f0 = aR * mix_w[(r16 * CIN + c0) * RR + r];
                    f1 = aR * mix_w[(r16 * CIN + c1) * RR + r];
                }
            }
            bf.u[jp] = pack_bf16(f0, f1);
        }
        bfrag[i] = bf.s;
    }
    const float bias = (r16 < 8) ? (aS * conv_b[r16] + aR * mix_b[r16]) : 0.0f;

    __syncthreads();

    const char* slabp = (const char*)slab;
    float* outb = out + ((size_t)blockIdx.x * BTB + btl) * (COUT * NNODES);

    // per-lane loop invariants for on-the-fly offsets
    const int  w_  = r16 & 7;       // w coordinate: t-invariant per lane
    const int  hb  = r16 >> 3;      // h = (2t + hb) & 7
    const int  j1  = (quad + 1) & 3;
    const bool q3  = (quad == 3);
    const int  s0d = (quad == 0) ? 0 : (quad == 1) ? -64 : (quad == 2) ? 64 : -8;
    const int  s1d = (quad == 0) ? 8 : (quad == 1) ? -1 : 1;
    const bool c1s = (quad == 1) ? (w_ > 0) : (quad == 2) ? (w_ < 7) : true;
    const int  base0 = (GUARD + r16 + s0d) * 16;  // + t*256 per iter
    const int  base1 = (GUARD + r16 + s1d) * 16;

    // 1-ahead prefetch of the two random node indices (coalesced, L1-hot)
    const int* rp = rand_idx + ((half * 16) * 16 + r16) * RR + j1;
    int nr1 = rp[0], nr2 = rp[4];

#pragma unroll 2
    for (int tt = 0; tt < 16; ++tt) {
        const int t = half * 16 + tt;
        const int rv1 = nr1, rv2 = nr2;
        if (tt < 15) { rp += 16 * RR; nr1 = rp[0]; nr2 = rp[4]; }

        const int tb = t << 8;                    // t*256 bytes (16 nodes * 16 B)
        const int h  = (2 * t + hb) & 7;
        int off0 = base0 + tb;                    // q0:center q1:d- q2:d+ q3:h-
        if (q3 && h == 0) off0 = 0;               // h- invalid at h==0 -> zero slot
        const bool ok1 = (quad == 0) ? (h < 7) : c1s;  // q0:h+ q1:w- q2:w+
        const int off1  = ok1 ? (base1 + tb) : 0;
        const int offr1 = (GUARD * 16) + (rv1 << 4);
        const int offr2 = (GUARD * 16) + (rv2 << 4);
        const int o0 = off0;
        const int o1 = q3 ? offr1 : off1;
        const int o2 = q3 ? offr2 : offr1;
        const int o3 = q3 ? 0 : offr2;

        union { uint4 u; short8 s; } r0, r1, r2, r3;  // 4x ds_read_b128
        r0.u = *(const uint4*)(slabp + o0);
        r1.u = *(const uint4*)(slabp + o1);
        r2.u = *(const uint4*)(slabp + o2);
        r3.u = *(const uint4*)(slabp + o3);

        floatx4 acc_a = {bias, bias, bias, bias};
        floatx4 acc_b = {0.0f, 0.0f, 0.0f, 0.0f};
        acc_a = __builtin_amdgcn_mfma_f32_16x16x32_bf16(r0.s, bfrag[0], acc_a, 0, 0, 0);
        acc_b = __builtin_amdgcn_mfma_f32_16x16x32_bf16(r2.s, bfrag[2], acc_b, 0, 0, 0);
        acc_a = __builtin_amdgcn_mfma_f32_16x16x32_bf16(r1.s, bfrag[1], acc_a, 0, 0, 0);
        acc_b = __builtin_amdgcn_mfma_f32_16x16x32_bf16(r3.s, bfrag[3], acc_b, 0, 0, 0);

        // C/D: col=lane&15 (=o), row=quad*4+reg (node within 16-tile)
        if (r16 < 8) {
            float4 res;
            res.x = acc_a.x + acc_b.x;
            res.y = acc_a.y + acc_b.y;
            res.z = acc_a.z + acc_b.z;
            res.w = acc_a.w + acc_b.w;
            *(float4*)(outb + r16 * NNODES + t * 16 + quad * 4) = res;
        }
    }
}

extern "C" void kernel_launch(void* const* d_in, const int* in_sizes, int n_in,
                              void* d_out, int out_size, void* d_ws, size_t ws_size,
                              hipStream_t stream) {
    const float* x       = (const float*)d_in[0];
    const float* conv_w  = (const float*)d_in[1];
    const float* conv_b  = (const float*)d_in[2];
    const float* mix_w   = (const float*)d_in[3];
    const float* mix_b   = (const float*)d_in[4];
    const float* alpha_p = (const float*)d_in[5];
    const int*   rand_i  = (const int*)d_in[6];
    float* out = (float*)d_out;
    (void)d_ws; (void)ws_size;

    const int BT = in_sizes[0] / (CIN * NNODES);   // 2048

    hybrid3d_v4<<<BT / BTB, 256, 0, stream>>>(x, conv_w, conv_b, mix_w, mix_b,
                                              alpha_p, rand_i, out);
}

// Round 2
// 104.514 us; speedup vs baseline: 1.0771x; 1.0771x over previous
//
#include <hip/hip_runtime.h>
#include <math.h>

#define NNODES 512
#define CIN 8
#define COUT 8
#define RR 8
#define BTB 2                          // bt items per block (2 waves per bt)
#define GUARD 64                       // zeroed guard node-slots each side
#define SLOTS (GUARD + NNODES + GUARD) // 640 node slots per bt
#define SLAB_HW (SLOTS * 8)            // 5120 halfwords per bt (16 B per node slot)
#define LDS_HW (BTB * SLAB_HW)         // 10240 hw = 20480 B -> 4+ blocks/CU
#define WTAB 1024                      // float offset of addr table in ws

typedef __attribute__((ext_vector_type(8))) short short8;
typedef __attribute__((ext_vector_type(4))) float floatx4;

__device__ __forceinline__ unsigned int pack_bf16(float a, float b) {
    unsigned int ua = __float_as_uint(a);
    unsigned int ub = __float_as_uint(b);
    ua = (ua + 0x7fffu + ((ua >> 16) & 1u)) >> 16;
    ub = (ub + 0x7fffu + ((ub >> 16) & 1u)) & 0xffff0000u;
    return ua | ub;
}

// ---- prep (PARALLEL: 12 blocks x 256): fold sigmoid(alpha) into weights/bias
// + per-(t,lane) LDS byte-offset table.
// ws floats [0..959]:  w[o][c][15] (0..6 = a*stencil taps, 7..14 = (1-a)*mix_w)
//          [960..967]: bias2[o]
// ws ints  [1024..1024+8192): int4 table[t*64+lane] = LDS byte offsets for MFMA i=0..3
// K = tap*8 + c. MFMA i covers taps {4i..4i+3}; quad q holds tap 4i+q.
// taps: 0 center, 1 d-, 2 d+, 3 h-, 4 h+, 5 w-, 6 w+, 7..14 g0..g7, 15 zero.
__global__ __launch_bounds__(256) void prep(
                     const float* __restrict__ conv_w,
                     const float* __restrict__ conv_b,
                     const float* __restrict__ mix_w,
                     const float* __restrict__ mix_b,
                     const float* __restrict__ alpha_p,
                     const int*   __restrict__ rand_idx,
                     float* __restrict__ ws) {
    const int gid = blockIdx.x * 256 + threadIdx.x;
    const float a = 1.0f / (1.0f + expf(-alpha_p[0]));

    if (gid < 2048) {
        // table entries (blocks 0..7)
        const int e = gid;
        const int tt = e >> 6, lane = e & 63;
        const int q = lane >> 4, r16 = lane & 15;
        const int m = tt * 16 + r16;
        const int h = (m >> 3) & 7, w = m & 7;
        int off[4];
#pragma unroll
        for (int i = 0; i < 4; ++i) {
            const int tap = 4 * i + q;
            int o;
            if (tap == 0)       o = GUARD + m;
            else if (tap == 1)  o = GUARD + m - 64;                    // d- (guard zero)
            else if (tap == 2)  o = GUARD + m + 64;                    // d+
            else if (tap == 3)  o = (h > 0) ? (GUARD + m - 8) : 0;     // h-
            else if (tap == 4)  o = (h < 7) ? (GUARD + m + 8) : 0;     // h+
            else if (tap == 5)  o = (w > 0) ? (GUARD + m - 1) : 0;     // w-
            else if (tap == 6)  o = (w < 7) ? (GUARD + m + 1) : 0;     // w+
            else if (tap <= 14) o = GUARD + rand_idx[m * RR + (tap - 7)];
            else                o = 0;                                 // tap15 -> zero slot
            off[i] = o * 16;   // bytes (16 B per node slot)
        }
        int4* tab = (int4*)((int*)ws + WTAB);
        tab[e] = make_int4(off[0], off[1], off[2], off[3]);
    } else {
        // weight/bias fold (blocks 8..11)
        const int k = gid - 2048;
        if (k < 960) {
            const int oc = k / 15;
            const int tap = k % 15;
            float v;
            if (tap < 7) {
                // (kd,kh,kw)->kd*9+kh*3+kw: center=13, d-=4, d+=22, h-=10, h+=16, w-=12, w+=14
                const int off7[7] = {13, 4, 22, 10, 16, 12, 14};
                v = a * conv_w[oc * 27 + off7[tap]];
            } else {
                v = (1.0f - a) * mix_w[oc * RR + (tap - 7)];
            }
            ws[k] = v;
        } else if (k < 968) {
            const int o = k - 960;
            ws[960 + o] = a * conv_b[o] + (1.0f - a) * mix_b[o];
        }
    }
}

// ---- main: node-major bf16 LDS slots, A-frag = 1 ds_read_b128, 2 waves per bt.
__global__ __launch_bounds__(256) void hybrid3d_v5(
    const float* __restrict__ x,
    const float* __restrict__ wsb,
    float* __restrict__ out)
{
    __shared__ unsigned short lds16[LDS_HW];
    const int tid  = threadIdx.x;
    const int wave = tid >> 6;
    const int lane = tid & 63;
    const int quad = lane >> 4;
    const int r16  = lane & 15;
    const int btl  = wave >> 1;     // bt within block (0..1)
    const int half = wave & 1;      // node-half handled by this wave

    // zero guard slots: 2 bt x 128 slots x 16 B -> exactly one uint4 per thread
    {
        const int b = tid >> 7;
        const int s = tid & 127;
        const int slot = (s < GUARD) ? s : (NNODES + s);   // 0..63 | 576..639
        *(uint4*)&lds16[b * SLAB_HW + slot * 8] = make_uint4(0u, 0u, 0u, 0u);
    }

    // B-fragments (weights) + bias, built once into VGPRs
    short8 bfrag[4];
#pragma unroll
    for (int i = 0; i < 4; ++i) {
        const int tap = 4 * i + quad;
        union { unsigned int u[4]; short8 s; } bf;
#pragma unroll
        for (int jp = 0; jp < 4; ++jp) {
            const int c0 = 2 * jp, c1 = 2 * jp + 1;
            float f0 = (r16 < 8 && tap < 15) ? wsb[(r16 * CIN + c0) * 15 + tap] : 0.0f;
            float f1 = (r16 < 8 && tap < 15) ? wsb[(r16 * CIN + c1) * 15 + tap] : 0.0f;
            bf.u[jp] = pack_bf16(f0, f1);
        }
        bfrag[i] = bf.s;
    }
    const float bias = (r16 < 8) ? wsb[960 + r16] : 0.0f;

    // stage x -> node-major bf16 slots (each wave stages its half of its bt)
    const float* xg = x + ((size_t)blockIdx.x * BTB + btl) * (CIN * NNODES);
    unsigned short* slab = lds16 + btl * SLAB_HW;
#pragma unroll
    for (int j = 0; j < 4; ++j) {
        const int n = half * 256 + j * 64 + lane;
        float v[8];
#pragma unroll
        for (int c = 0; c < 8; ++c) v[c] = xg[c * NNODES + n];
        uint4 pk;
        pk.x = pack_bf16(v[0], v[1]);
        pk.y = pack_bf16(v[2], v[3]);
        pk.z = pack_bf16(v[4], v[5]);
        pk.w = pack_bf16(v[6], v[7]);
        *(uint4*)&slab[(GUARD + n) * 8] = pk;
    }
    __syncthreads();

    const char* slabp = (const char*)slab;
    const int4* tab = (const int4*)((const int*)wsb + WTAB);
    float* outb = out + ((size_t)blockIdx.x * BTB + btl) * (COUT * NNODES);

    // 1-ahead prefetch of the offset table entry (coalesced, L1-resident)
    int4 off = tab[(half * 16) * 64 + lane];

#pragma unroll 4
    for (int tt = 0; tt < 16; ++tt) {
        const int t = half * 16 + tt;
        const int4 cur = off;
        if (tt < 15) off = tab[(t + 1) * 64 + lane];

        union { uint4 u; short8 s; } r0, r1, r2, r3;  // 4x ds_read_b128
        r0.u = *(const uint4*)(slabp + cur.x);
        r1.u = *(const uint4*)(slabp + cur.y);
        r2.u = *(const uint4*)(slabp + cur.z);
        r3.u = *(const uint4*)(slabp + cur.w);

        floatx4 acc_a = {bias, bias, bias, bias};
        floatx4 acc_b = {0.0f, 0.0f, 0.0f, 0.0f};
        acc_a = __builtin_amdgcn_mfma_f32_16x16x32_bf16(r0.s, bfrag[0], acc_a, 0, 0, 0);
        acc_b = __builtin_amdgcn_mfma_f32_16x16x32_bf16(r2.s, bfrag[2], acc_b, 0, 0, 0);
        acc_a = __builtin_amdgcn_mfma_f32_16x16x32_bf16(r1.s, bfrag[1], acc_a, 0, 0, 0);
        acc_b = __builtin_amdgcn_mfma_f32_16x16x32_bf16(r3.s, bfrag[3], acc_b, 0, 0, 0);

        // C/D: col=lane&15 (=o), row=quad*4+reg (node within 16-tile)
        if (r16 < 8) {
            float4 res;
            res.x = acc_a.x + acc_b.x;
            res.y = acc_a.y + acc_b.y;
            res.z = acc_a.z + acc_b.z;
            res.w = acc_a.w + acc_b.w;
            *(float4*)(outb + r16 * NNODES + t * 16 + quad * 4) = res;
        }
    }
}

extern "C" void kernel_launch(void* const* d_in, const int* in_sizes, int n_in,
                              void* d_out, int out_size, void* d_ws, size_t ws_size,
                              hipStream_t stream) {
    const float* x       = (const float*)d_in[0];
    const float* conv_w  = (const float*)d_in[1];
    const float* conv_b  = (const float*)d_in[2];
    const float* mix_w   = (const float*)d_in[3];
    const float* mix_b   = (const float*)d_in[4];
    const float* alpha_p = (const float*)d_in[5];
    const int*   rand_i  = (const int*)d_in[6];
    float* out = (float*)d_out;
    float* ws  = (float*)d_ws;

    const int BT = in_sizes[0] / (CIN * NNODES);   // 2048

    prep<<<12, 256, 0, stream>>>(conv_w, conv_b, mix_w, mix_b, alpha_p, rand_i, ws);
    hybrid3d_v5<<<BT / BTB, 256, 0, stream>>>(x, ws, out);
}